// Round 19
// baseline (71.958 us; speedup 1.0000x reference)
//
#include <hip/hip_runtime.h>

namespace {

constexpr int T = 4096;
constexpr int C = 128;
constexpr int H = 8;
constexpr int D = 16;
constexpr int BH = 16;                         // B*H
constexpr size_t PLANE = (size_t)BH * T * D;   // 1,048,576 elements per tensor
constexpr int NTILE = T / 32;                  // 128 key-tiles per bh
constexpr int VROWS = 17;                      // 16 d-rows + 1 ones-row
constexpr size_t VPLANE = (size_t)NTILE * VROWS * 32;  // per-bh Vt elements

using bf16x8 = __attribute__((ext_vector_type(8))) short;
using f32x16 = __attribute__((ext_vector_type(16))) float;

__device__ __forceinline__ uint32_t cvt_pk_bf16(float lo, float hi) {
  uint32_t r;
  asm("v_cvt_pk_bf16_f32 %0, %1, %2" : "=v"(r) : "v"(lo), "v"(hi));
  return r;
}
__device__ __forceinline__ float exp2_hw(float x) {
  float r;
  asm("v_exp_f32 %0, %1" : "=v"(r) : "v"(x));
  return r;
}
// async global->LDS, 16B per lane: lds dest = uniform base + lane*16.
typedef const __attribute__((address_space(1))) void* gas_t;
typedef __attribute__((address_space(3))) void* las_t;
__device__ __forceinline__ void gload_lds16(const void* g, void* l) {
  __builtin_amdgcn_global_load_lds((gas_t)g, (las_t)l, 16, 0, 0);
}

// ---------------------------------------------------------------------------
// Kernel 1: QKV projection -> bf16.  Half-K LDS staging (34.8KB, 4 blk/CU).
//   Qbf[bh][t][d] (pre-scaled by D^-1/2*log2e), Kbf[bh][t][d],
//   Vt TILED+ONES+SWIZZLED: [bh][t/32][17][32].
// NEW (r19): V epilogue writes each (head,tile) unit as one fully-contiguous
// 1024B wave burst (lane l -> tilebase + l*16), gathering from Ls with the
// inverse swizzle.  The old path stored 8B granules at 64B strides --
// partial-line writes (L2 RMW sectors); prime suspect for the cross-round
// ~30us "non-attn" mass (r1's pre-bf16 qkv ran in ~2-3us; the cost appeared
// with r2's V-store rewrite).  Output bytes identical.
// ---------------------------------------------------------------------------
__global__ __launch_bounds__(256) void qkv_proj(
    const float* __restrict__ x, const float* __restrict__ Wq,
    const float* __restrict__ Wk, const float* __restrict__ Wv,
    unsigned short* __restrict__ Qbf, unsigned short* __restrict__ Kbf,
    unsigned short* __restrict__ Vt) {
  __shared__ float Xs[64][68];  // [k][m]  17.4KB
  __shared__ float Ws[64][68];  // [k][n]  17.4KB
  const int tid = threadIdx.x;
  const int bm = blockIdx.x;            // 128 row blocks
  const int bn = blockIdx.y;            // 6 col blocks
  const int mat = bn >> 1;              // 0=Q 1=K 2=V
  const int c0 = (bn & 1) * 64;
  const float* W = (mat == 0) ? Wq : (mat == 1) ? Wk : Wv;
  const int t0 = bm * 64;
  const int tx = tid & 15, ty = tid >> 4;

  float acc[4][4] = {};
#pragma unroll 1
  for (int kh = 0; kh < 2; ++kh) {
    if (kh) __syncthreads();
    for (int f = tid; f < 1024; f += 256) {
      const int m = f >> 4;
      const int k4 = (f & 15) << 2;
      const float4 v =
          *(const float4*)(x + (size_t)(t0 + m) * C + kh * 64 + k4);
      Xs[k4 + 0][m] = v.x; Xs[k4 + 1][m] = v.y;
      Xs[k4 + 2][m] = v.z; Xs[k4 + 3][m] = v.w;
      const float4 u =
          *(const float4*)(W + (size_t)(c0 + m) * C + kh * 64 + k4);
      Ws[k4 + 0][m] = u.x; Ws[k4 + 1][m] = u.y;
      Ws[k4 + 2][m] = u.z; Ws[k4 + 3][m] = u.w;
    }
    __syncthreads();
#pragma unroll 8
    for (int k = 0; k < 64; ++k) {
      const float4 a = *(const float4*)&Xs[k][ty * 4];
      const float4 b = *(const float4*)&Ws[k][tx * 4];
      const float av[4] = {a.x, a.y, a.z, a.w};
      const float bv[4] = {b.x, b.y, b.z, b.w};
#pragma unroll
      for (int i = 0; i < 4; ++i)
#pragma unroll
        for (int j = 0; j < 4; ++j) acc[i][j] = fmaf(av[i], bv[j], acc[i][j]);
    }
  }
  __syncthreads();  // done reading Xs -> reuse as bf16 staging

  unsigned short* Ls = (unsigned short*)&Xs[0][0];  // [64][72] bf16
  if (mat < 2) {
    const float sc = (mat == 0) ? 0.25f * 1.4426950408889634f : 1.0f;
#pragma unroll
    for (int i = 0; i < 4; ++i) {
      const uint32_t u0 = cvt_pk_bf16(acc[i][0] * sc, acc[i][1] * sc);
      const uint32_t u1 = cvt_pk_bf16(acc[i][2] * sc, acc[i][3] * sc);
      *(uint32_t*)&Ls[(ty * 4 + i) * 72 + tx * 4]     = u0;
      *(uint32_t*)&Ls[(ty * 4 + i) * 72 + tx * 4 + 2] = u1;
    }
    __syncthreads();
    unsigned short* dst = (mat == 0) ? Qbf : Kbf;
    const int lane = tid & 63, hp = tid >> 6;
    const int tr = t0 + lane, b = tr >> 12, t = tr & (T - 1);
    const int head = (c0 >> 4) + hp;
    unsigned short* base = dst + (((size_t)(b * H + head)) * T + t) * D;
#pragma unroll
    for (int p = 0; p < 2; ++p)
      *(uint4*)(base + p * 8) = *(const uint4*)&Ls[lane * 72 + hp * 16 + p * 8];
  } else {
#pragma unroll
    for (int j = 0; j < 4; ++j) {       // Ls[c][t] (transposed)
      const uint32_t u0 = cvt_pk_bf16(acc[0][j], acc[1][j]);
      const uint32_t u1 = cvt_pk_bf16(acc[2][j], acc[3][j]);
      *(uint32_t*)&Ls[(tx * 4 + j) * 72 + ty * 4]     = u0;
      *(uint32_t*)&Ls[(tx * 4 + j) * 72 + ty * 4 + 2] = u1;
    }
    __syncthreads();
    // NEW coalesced V writer: wave w2 handles units 2*w2, 2*w2+1
    // (unit = head-offset ho (0..3) x tile ti (0..1)).  Lane l packs the 8
    // swizzled bf16 of row d = l>>2, group g = l&3 and stores 16B at
    // tilebase + l*16: one contiguous 1024B burst per unit.
    const int w2 = tid >> 6, l = tid & 63;
    const int b = t0 >> 12;
    const int tile0 = (t0 & (T - 1)) >> 5;        // t0 is 64-aligned
    const int d = l >> 2, g = l & 3;
    const int kbase = 16 * (g & 1) + 4 * (g >> 1);
#pragma unroll
    for (int u = 2 * w2; u < 2 * w2 + 2; ++u) {
      const int ho = u >> 1, ti = u & 1;
      const int head = (c0 >> 4) + ho;
      const unsigned short* Lsrc = Ls + (ho * 16 + d) * 72 + ti * 32;
      uint32_t pk[4];
#pragma unroll
      for (int p = 0; p < 4; ++p) {
        const int kk = kbase + 8 * (p >> 1) + 2 * (p & 1);
        pk[p] = (uint32_t)Lsrc[kk] | ((uint32_t)Lsrc[kk + 1] << 16);
      }
      unsigned short* tb =
          Vt + ((size_t)(b * H + head) * NTILE + tile0 + ti) * (VROWS * 32);
      *(uint4*)((char*)tb + l * 16) = make_uint4(pk[0], pk[1], pk[2], pk[3]);
    }
    // ones row (row 16) for the 4 heads x 2 tiles this block owns
    if (tid < 8) {
      const int headx = (c0 >> 4) + (tid >> 1);
      const int tilex = tile0 + (tid & 1);
      unsigned short* orow =
          Vt + (((size_t)(b * H + headx) * NTILE + tilex) * VROWS + 16) * 32;
      const uint4 ones = make_uint4(0x3F803F80u, 0x3F803F80u,
                                    0x3F803F80u, 0x3F803F80u);
#pragma unroll
      for (int q = 0; q < 4; ++q) *(uint4*)(orow + q * 8) = ones;
    }
  }
}

// ---------------------------------------------------------------------------
// Kernel 2: causal flash attention (r18 best: barrier-free per-wave LDS
// pipeline, counted vmcnt, no-max softmax, ones-row denominator).  Unchanged.
// ---------------------------------------------------------------------------
__global__ __launch_bounds__(512, 2) void attn_fwd(
    const unsigned short* __restrict__ Qbf, const unsigned short* __restrict__ Kbf,
    const unsigned short* __restrict__ Vt, float* __restrict__ att) {
  __shared__ __align__(16) char smem[50688];   // slots [8][3][2112] U Po
  float (*Po)[2][32][17] = reinterpret_cast<float(*)[2][32][17]>(smem);
  const int tid = threadIdx.x;
  const int w = tid >> 6, l = tid & 63;
  const int lane31 = l & 31, h = l >> 5;
  const int dvx = (lane31 == 16) ? 16 : (l & 15);  // lane31==16 -> ones row
  const int ib = blockIdx.x;
  const int bh = 2 * (ib & 7) + ((ib >> 3) & 1);   // XCD x <- bh {2x, 2x+1}
  const int j = ib >> 4;                           // 0..31
  const int superA = 63 - j, superB = j;
  const int nsA = 2 * superA + 2, nsB = 2 * superB + 2;  // nsA >= 66

  const unsigned short* Qp = Qbf + (size_t)bh * T * D;
  const unsigned short* Kp = Kbf + (size_t)bh * T * D;
  const unsigned short* Vp = Vt + (size_t)bh * VPLANE;

  auto half_step = [&](const bf16x8& kf, const bf16x8& vA, const bf16x8& vB,
                       const bf16x8& qf, f32x16& acc, int s, int tq,
                       int qidx) {
    f32x16 sc = {};
    __builtin_amdgcn_s_setprio(1);
    sc = __builtin_amdgcn_mfma_f32_32x32x16_bf16(kf, qf, sc, 0, 0, 0);
    __builtin_amdgcn_s_setprio(0);
    if (s >= tq) {                      // diag or dead step: causal mask
      const int k0 = s * 32;
#pragma unroll
      for (int r = 0; r < 16; ++r) {
        const int key = k0 + (r & 3) + 8 * (r >> 2) + 4 * h;
        if (key > qidx) sc[r] = -1e30f;
      }
    }
#pragma unroll
    for (int r = 0; r < 16; ++r) sc[r] = exp2_hw(sc[r]);  // no-max softmax
    union PF { bf16x8 v; uint32_t u[4]; } pa, pb;
    pa.u[0] = cvt_pk_bf16(sc[0], sc[1]);
    pa.u[1] = cvt_pk_bf16(sc[2], sc[3]);
    pa.u[2] = cvt_pk_bf16(sc[4], sc[5]);
    pa.u[3] = cvt_pk_bf16(sc[6], sc[7]);
    pb.u[0] = cvt_pk_bf16(sc[8], sc[9]);
    pb.u[1] = cvt_pk_bf16(sc[10], sc[11]);
    pb.u[2] = cvt_pk_bf16(sc[12], sc[13]);
    pb.u[3] = cvt_pk_bf16(sc[14], sc[15]);
    __builtin_amdgcn_s_setprio(1);
    acc = __builtin_amdgcn_mfma_f32_32x32x16_bf16(vA, pa.v, acc, 0, 0, 0);
    acc = __builtin_amdgcn_mfma_f32_32x32x16_bf16(vB, pb.v, acc, 0, 0, 0);
    __builtin_amdgcn_s_setprio(0);
  };

  auto run_phase = [&](int sup, int ns) {
    char* sA = smem + w * 6336;         // my 3 slots
    char* sB = sA + 2112;
    char* sC = sA + 4224;
    // prefill constant bf16(1.0) ones rows of my 3 slots (wave-private)
    if (l < 48)
      *(uint32_t*)(sA + (l >> 4) * 2112 + 2048 + (l & 15) * 4) = 0x3F803F80u;
    asm volatile("s_waitcnt lgkmcnt(0)" ::: "memory");

    const int tq0 = 2 * sup, tq1 = 2 * sup + 1;
    const int qidx0 = sup * 64 + lane31, qidx1 = qidx0 + 32;
    const bf16x8 qf0 = *(const bf16x8*)(Qp + (size_t)qidx0 * D + 8 * h);
    const bf16x8 qf1 = *(const bf16x8*)(Qp + (size_t)qidx1 * D + 8 * h);
    f32x16 acc0 = {}, acc1 = {};

    const int cnt = (w < ns) ? ((ns - w + 7) >> 3) : 0;
    auto stage = [&](char* slot, int i) {         // always exactly 2 loads
      int s = w + 8 * i;
      if (s > NTILE - 1) s = NTILE - 1;           // clamped: always legal
      gload_lds16((const char*)Kp + (size_t)s * 1024 + (size_t)l * 16, slot);
      gload_lds16((const char*)Vp + (size_t)s * 1088 + (size_t)l * 16,
                  slot + 1024);
    };
    stage(sA, 0); stage(sB, 1); stage(sC, 2);     // prologue: depth 3

    char* cur = sA; char* nx1 = sB; char* nx2 = sC;
#pragma unroll 1
    for (int i = 0; i < cnt; ++i) {
      const int s = w + 8 * i;
      asm volatile("s_waitcnt vmcnt(4)" ::: "memory");  // slot `cur` landed
      __builtin_amdgcn_sched_barrier(0);
      const unsigned short* kb = (const unsigned short*)cur;
      const unsigned short* vb = (const unsigned short*)(cur + 1024);
      const bf16x8 kf = *(const bf16x8*)(kb + lane31 * 16 + 8 * h);
      const bf16x8 vA = *(const bf16x8*)(vb + dvx * 32 + 16 * h);
      const bf16x8 vBv = *(const bf16x8*)(vb + dvx * 32 + 16 * h + 8);
      half_step(kf, vA, vBv, qf0, acc0, s, tq0, qidx0);
      half_step(kf, vA, vBv, qf1, acc1, s, tq1, qidx1);
      asm volatile("s_waitcnt lgkmcnt(0)" ::: "memory");  // reads retired
      __builtin_amdgcn_sched_barrier(0);
      stage(cur, i + 3);                 // reuse just-consumed slot
      char* t = cur; cur = nx1; nx1 = nx2; nx2 = t;
    }
    asm volatile("s_waitcnt vmcnt(0)" ::: "memory");  // tail stages land
    __syncthreads();                     // kv region quiesced for Po reuse

#pragma unroll
    for (int r = 0; r < 8; ++r) {
      const int dj = (r & 3) + 8 * (r >> 2) + 4 * h;
      Po[w][0][lane31][dj] = acc0[r];
      Po[w][1][lane31][dj] = acc1[r];
    }
    if (l < 32) {                        // row 16 = sum(P)  (ones row)
      Po[w][0][lane31][16] = acc0[8];
      Po[w][1][lane31][16] = acc1[8];
    }
  };

  auto merge = [&](int sup, int tt) {
    const int qidx = sup * 64 + tt * 32 + lane31;
    float L = 0.f, od[8] = {};
#pragma unroll
    for (int p = 0; p < 8; ++p) {
      L += Po[p][tt][lane31][16];
#pragma unroll
      for (int r = 0; r < 8; ++r) {
        const int dj = (r & 3) + 8 * (r >> 2) + 4 * h;
        od[r] += Po[p][tt][lane31][dj];
      }
    }
    const float inv = 1.f / L;
    float* base = att + ((size_t)bh * T + qidx) * D;
    *(float4*)(base + 4 * h) =
        make_float4(od[0] * inv, od[1] * inv, od[2] * inv, od[3] * inv);
    *(float4*)(base + 8 + 4 * h) =
        make_float4(od[4] * inv, od[5] * inv, od[6] * inv, od[7] * inv);
  };

  run_phase(superA, nsA);
  __syncthreads();
  if (w < 2) merge(superA, w);
  __syncthreads();                       // Po consumed; slots reusable
  run_phase(superB, nsB);
  __syncthreads();
  if (w < 2) merge(superB, w);
}

// ---------------------------------------------------------------------------
// Kernel 3: output projection + bias (fp32).  Half-K staging, 512 blocks.
// (unchanged)
// ---------------------------------------------------------------------------
__global__ __launch_bounds__(256) void out_proj(
    const float* __restrict__ att, const float* __restrict__ Wp,
    const float* __restrict__ bp, float* __restrict__ out) {
  __shared__ float As[64][36];
  __shared__ float Bs[64][68];
  const int tid = threadIdx.x;
  const int t0 = blockIdx.x * 32;
  const int c0 = blockIdx.y * 64;
  const int tx = tid & 15, ty = tid >> 4;

  float acc[2][4] = {};
#pragma unroll 1
  for (int kh = 0; kh < 2; ++kh) {
    if (kh) __syncthreads();
    for (int f = tid; f < 512; f += 256) {
      const int mm = f & 31;
      const int cpl = (f >> 5) << 2;
      const int cp = kh * 64 + cpl;
      const int tr = t0 + mm;
      const int b = tr >> 12, t = tr & (T - 1);
      const int hh = cp >> 4, d0 = cp & 15;
      const float4 v =
          *(const float4*)(att + (((size_t)b * H + hh) * T + t) * D + d0);
      As[cpl + 0][mm] = v.x; As[cpl + 1][mm] = v.y;
      As[cpl + 2][mm] = v.z; As[cpl + 3][mm] = v.w;
    }
    for (int f = tid; f < 1024; f += 256) {
      const int n = f >> 4;
      const int kk = (f & 15) << 2;
      const float4 v =
          *(const float4*)(Wp + (size_t)(c0 + n) * C + kh * 64 + kk);
      Bs[kk + 0][n] = v.x; Bs[kk + 1][n] = v.y;
      Bs[kk + 2][n] = v.z; Bs[kk + 3][n] = v.w;
    }
    __syncthreads();
#pragma unroll 8
    for (int k = 0; k < 64; ++k) {
      const float2 a = *(const float2*)&As[k][ty * 2];
      const float4 b = *(const float4*)&Bs[k][tx * 4];
      const float av[2] = {a.x, a.y};
      const float bv[4] = {b.x, b.y, b.z, b.w};
#pragma unroll
      for (int i = 0; i < 2; ++i)
#pragma unroll
        for (int jj = 0; jj < 4; ++jj)
          acc[i][jj] = fmaf(av[i], bv[jj], acc[i][jj]);
    }
  }

  const float4 bias = *(const float4*)(bp + c0 + tx * 4);
#pragma unroll
  for (int i = 0; i < 2; ++i) {
    const int tr = t0 + ty * 2 + i;
    const float4 v = make_float4(acc[i][0] + bias.x, acc[i][1] + bias.y,
                                 acc[i][2] + bias.z, acc[i][3] + bias.w);
    *(float4*)(out + (size_t)tr * C + c0 + tx * 4) = v;
  }
}

}  // namespace

extern "C" void kernel_launch(void* const* d_in, const int* in_sizes, int n_in,
                              void* d_out, int out_size, void* d_ws, size_t ws_size,
                              hipStream_t stream) {
  // setup_inputs order: x, Wk, Wq, Wv, Wp, bp
  const float* x  = (const float*)d_in[0];
  const float* Wk = (const float*)d_in[1];
  const float* Wq = (const float*)d_in[2];
  const float* Wv = (const float*)d_in[3];
  const float* Wp = (const float*)d_in[4];
  const float* bp = (const float*)d_in[5];

  float* att = (float*)d_ws;                             // 4 MiB fp32
  unsigned short* Qbf = (unsigned short*)(att + PLANE);  // 2 MiB bf16
  unsigned short* Kbf = Qbf + PLANE;                     // 2 MiB
  unsigned short* Vtb = Kbf + PLANE;                     // ~2.13 MiB (VROWS=17)

  // DIAGNOSTIC (this round only): qkv_proj launched TWICE (idempotent,
  // deterministic) -- its runtime shows up as the dur_us delta vs r18,
  // giving the per-kernel split the fill-dominated top-5 can't.
  qkv_proj<<<dim3(128, 6), 256, 0, stream>>>(x, Wq, Wk, Wv, Qbf, Kbf, Vtb);
  qkv_proj<<<dim3(128, 6), 256, 0, stream>>>(x, Wq, Wk, Wv, Qbf, Kbf, Vtb);
  attn_fwd<<<dim3(512), 512, 0, stream>>>(Qbf, Kbf, Vtb, att);
  out_proj<<<dim3(256, 2), 256, 0, stream>>>(att, Wp, bp, (float*)d_out);
}

// Round 20
// 59.447 us; speedup vs baseline: 1.2105x; 1.2105x over previous
//
#include <hip/hip_runtime.h>

namespace {

constexpr int T = 4096;
constexpr int C = 128;
constexpr int H = 8;
constexpr int D = 16;
constexpr int BH = 16;                         // B*H
constexpr size_t PLANE = (size_t)BH * T * D;   // 1,048,576 elements per tensor
constexpr int NTILE = T / 32;                  // 128 key-tiles per bh
constexpr int VROWS = 17;                      // 16 d-rows + 1 ones-row
constexpr size_t VPLANE = (size_t)NTILE * VROWS * 32;  // per-bh Vt elements

using bf16x8 = __attribute__((ext_vector_type(8))) short;
using f32x16 = __attribute__((ext_vector_type(16))) float;

__device__ __forceinline__ uint32_t cvt_pk_bf16(float lo, float hi) {
  uint32_t r;
  asm("v_cvt_pk_bf16_f32 %0, %1, %2" : "=v"(r) : "v"(lo), "v"(hi));
  return r;
}
__device__ __forceinline__ float exp2_hw(float x) {
  float r;
  asm("v_exp_f32 %0, %1" : "=v"(r) : "v"(x));
  return r;
}
// async global->LDS, 16B per lane: lds dest = uniform base + lane*16.
typedef const __attribute__((address_space(1))) void* gas_t;
typedef __attribute__((address_space(3))) void* las_t;
__device__ __forceinline__ void gload_lds16(const void* g, void* l) {
  __builtin_amdgcn_global_load_lds((gas_t)g, (las_t)l, 16, 0, 0);
}

// ---------------------------------------------------------------------------
// Kernel 1: QKV projection -> bf16.  r19 diag measured this kernel at 16.4us
// (3x its 5us VALU floor) at 12 waves/CU.  NOW: 512 threads/block, 2x4 acc
// per thread -- same 64x64 tile, same LDS (34.8KB), same per-output fmaf
// chain in the same k-order (bit-identical results), but 24 waves/CU and
// half the per-wave serial work between barriers.  No launch_bounds min-wave
// cap (the r4/6/8 spill trap); body is small enough to stay under 64 VGPR.
//   Qbf[bh][t][d] (pre-scaled by D^-1/2*log2e), Kbf[bh][t][d],
//   Vt TILED+ONES+SWIZZLED: [bh][t/32][17][32], V written as 1KB bursts.
// ---------------------------------------------------------------------------
__global__ __launch_bounds__(512) void qkv_proj(
    const float* __restrict__ x, const float* __restrict__ Wq,
    const float* __restrict__ Wk, const float* __restrict__ Wv,
    unsigned short* __restrict__ Qbf, unsigned short* __restrict__ Kbf,
    unsigned short* __restrict__ Vt) {
  __shared__ float Xs[64][68];  // [k][m]  17.4KB
  __shared__ float Ws[64][68];  // [k][n]  17.4KB
  const int tid = threadIdx.x;
  const int bm = blockIdx.x;            // 128 row blocks
  const int bn = blockIdx.y;            // 6 col blocks
  const int mat = bn >> 1;              // 0=Q 1=K 2=V
  const int c0 = (bn & 1) * 64;
  const float* W = (mat == 0) ? Wq : (mat == 1) ? Wk : Wv;
  const int t0 = bm * 64;
  const int tx = tid & 15, ty = tid >> 4;   // ty 0..31: 2 rows each

  float acc[2][4] = {};
#pragma unroll 1
  for (int kh = 0; kh < 2; ++kh) {
    if (kh) __syncthreads();            // prior pass's reads complete
    for (int f = tid; f < 1024; f += 512) {
      const int m = f >> 4;             // 0..63
      const int k4 = (f & 15) << 2;     // 0..60
      const float4 v =
          *(const float4*)(x + (size_t)(t0 + m) * C + kh * 64 + k4);
      Xs[k4 + 0][m] = v.x; Xs[k4 + 1][m] = v.y;
      Xs[k4 + 2][m] = v.z; Xs[k4 + 3][m] = v.w;
      const float4 u =
          *(const float4*)(W + (size_t)(c0 + m) * C + kh * 64 + k4);
      Ws[k4 + 0][m] = u.x; Ws[k4 + 1][m] = u.y;
      Ws[k4 + 2][m] = u.z; Ws[k4 + 3][m] = u.w;
    }
    __syncthreads();
#pragma unroll 8
    for (int k = 0; k < 64; ++k) {
      const float2 a = *(const float2*)&Xs[k][ty * 2];
      const float4 b = *(const float4*)&Ws[k][tx * 4];
      const float av[2] = {a.x, a.y};
      const float bv[4] = {b.x, b.y, b.z, b.w};
#pragma unroll
      for (int i = 0; i < 2; ++i)
#pragma unroll
        for (int j = 0; j < 4; ++j) acc[i][j] = fmaf(av[i], bv[j], acc[i][j]);
    }
  }
  __syncthreads();  // done reading Xs -> reuse as bf16 staging

  unsigned short* Ls = (unsigned short*)&Xs[0][0];  // [64][72] bf16, 9.2KB
  if (mat < 2) {
    const float sc = (mat == 0) ? 0.25f * 1.4426950408889634f : 1.0f;
#pragma unroll
    for (int i = 0; i < 2; ++i) {                 // Ls[t][c] packed bf16
      const uint32_t u0 = cvt_pk_bf16(acc[i][0] * sc, acc[i][1] * sc);
      const uint32_t u1 = cvt_pk_bf16(acc[i][2] * sc, acc[i][3] * sc);
      *(uint32_t*)&Ls[(ty * 2 + i) * 72 + tx * 4]     = u0;
      *(uint32_t*)&Ls[(ty * 2 + i) * 72 + tx * 4 + 2] = u1;
    }
    __syncthreads();
    unsigned short* dst = (mat == 0) ? Qbf : Kbf;
    const int lane = tid & 63, hp8 = tid >> 6;    // 8 slots: head x half
    const int tr = t0 + lane, b = tr >> 12, t = tr & (T - 1);
    const int head = (c0 >> 4) + (hp8 >> 1), p = hp8 & 1;
    *(uint4*)(dst + (((size_t)(b * H + head)) * T + t) * D + p * 8) =
        *(const uint4*)&Ls[lane * 72 + (hp8 >> 1) * 16 + p * 8];
  } else {
#pragma unroll
    for (int j = 0; j < 4; ++j) {                 // Ls[c][t] (transposed)
      const uint32_t u0 = cvt_pk_bf16(acc[0][j], acc[1][j]);
      *(uint32_t*)&Ls[(tx * 4 + j) * 72 + ty * 2] = u0;
    }
    __syncthreads();
    // coalesced V writer (r19): wave w2 -> unit (head-offset, tile); lane l
    // packs 8 swizzled bf16 of row d=l>>2, group g=l&3 and stores 16B at
    // tilebase + l*16: one contiguous 1024B burst per unit.
    const int w2 = tid >> 6, l = tid & 63;        // w2 0..7 = 4 heads x 2 tiles
    const int b = t0 >> 12;
    const int tile0 = (t0 & (T - 1)) >> 5;
    const int d = l >> 2, g = l & 3;
    const int kbase = 16 * (g & 1) + 4 * (g >> 1);
    {
      const int ho = w2 >> 1, ti = w2 & 1;
      const int head = (c0 >> 4) + ho;
      const unsigned short* Lsrc = Ls + (ho * 16 + d) * 72 + ti * 32;
      uint32_t pk[4];
#pragma unroll
      for (int p = 0; p < 4; ++p) {
        const int kk = kbase + 8 * (p >> 1) + 2 * (p & 1);
        pk[p] = (uint32_t)Lsrc[kk] | ((uint32_t)Lsrc[kk + 1] << 16);
      }
      unsigned short* tb =
          Vt + ((size_t)(b * H + head) * NTILE + tile0 + ti) * (VROWS * 32);
      *(uint4*)((char*)tb + l * 16) = make_uint4(pk[0], pk[1], pk[2], pk[3]);
    }
    // ones row (row 16) for the 4 heads x 2 tiles this block owns
    if (tid < 8) {
      const int headx = (c0 >> 4) + (tid >> 1);
      const int tilex = tile0 + (tid & 1);
      unsigned short* orow =
          Vt + (((size_t)(b * H + headx) * NTILE + tilex) * VROWS + 16) * 32;
      const uint4 ones = make_uint4(0x3F803F80u, 0x3F803F80u,
                                    0x3F803F80u, 0x3F803F80u);
#pragma unroll
      for (int q = 0; q < 4; ++q) *(uint4*)(orow + q * 8) = ones;
    }
  }
}

// ---------------------------------------------------------------------------
// Kernel 2: causal flash attention (r18: barrier-free per-wave LDS pipeline,
// counted vmcnt, no-max softmax, ones-row denominator).  Unchanged.
// ---------------------------------------------------------------------------
__global__ __launch_bounds__(512, 2) void attn_fwd(
    const unsigned short* __restrict__ Qbf, const unsigned short* __restrict__ Kbf,
    const unsigned short* __restrict__ Vt, float* __restrict__ att) {
  __shared__ __align__(16) char smem[50688];   // slots [8][3][2112] U Po
  float (*Po)[2][32][17] = reinterpret_cast<float(*)[2][32][17]>(smem);
  const int tid = threadIdx.x;
  const int w = tid >> 6, l = tid & 63;
  const int lane31 = l & 31, h = l >> 5;
  const int dvx = (lane31 == 16) ? 16 : (l & 15);  // lane31==16 -> ones row
  const int ib = blockIdx.x;
  const int bh = 2 * (ib & 7) + ((ib >> 3) & 1);   // XCD x <- bh {2x, 2x+1}
  const int j = ib >> 4;                           // 0..31
  const int superA = 63 - j, superB = j;
  const int nsA = 2 * superA + 2, nsB = 2 * superB + 2;  // nsA >= 66

  const unsigned short* Qp = Qbf + (size_t)bh * T * D;
  const unsigned short* Kp = Kbf + (size_t)bh * T * D;
  const unsigned short* Vp = Vt + (size_t)bh * VPLANE;

  auto half_step = [&](const bf16x8& kf, const bf16x8& vA, const bf16x8& vB,
                       const bf16x8& qf, f32x16& acc, int s, int tq,
                       int qidx) {
    f32x16 sc = {};
    __builtin_amdgcn_s_setprio(1);
    sc = __builtin_amdgcn_mfma_f32_32x32x16_bf16(kf, qf, sc, 0, 0, 0);
    __builtin_amdgcn_s_setprio(0);
    if (s >= tq) {                      // diag or dead step: causal mask
      const int k0 = s * 32;
#pragma unroll
      for (int r = 0; r < 16; ++r) {
        const int key = k0 + (r & 3) + 8 * (r >> 2) + 4 * h;
        if (key > qidx) sc[r] = -1e30f;
      }
    }
#pragma unroll
    for (int r = 0; r < 16; ++r) sc[r] = exp2_hw(sc[r]);  // no-max softmax
    union PF { bf16x8 v; uint32_t u[4]; } pa, pb;
    pa.u[0] = cvt_pk_bf16(sc[0], sc[1]);
    pa.u[1] = cvt_pk_bf16(sc[2], sc[3]);
    pa.u[2] = cvt_pk_bf16(sc[4], sc[5]);
    pa.u[3] = cvt_pk_bf16(sc[6], sc[7]);
    pb.u[0] = cvt_pk_bf16(sc[8], sc[9]);
    pb.u[1] = cvt_pk_bf16(sc[10], sc[11]);
    pb.u[2] = cvt_pk_bf16(sc[12], sc[13]);
    pb.u[3] = cvt_pk_bf16(sc[14], sc[15]);
    __builtin_amdgcn_s_setprio(1);
    acc = __builtin_amdgcn_mfma_f32_32x32x16_bf16(vA, pa.v, acc, 0, 0, 0);
    acc = __builtin_amdgcn_mfma_f32_32x32x16_bf16(vB, pb.v, acc, 0, 0, 0);
    __builtin_amdgcn_s_setprio(0);
  };

  auto run_phase = [&](int sup, int ns) {
    char* sA = smem + w * 6336;         // my 3 slots
    char* sB = sA + 2112;
    char* sC = sA + 4224;
    // prefill constant bf16(1.0) ones rows of my 3 slots (wave-private)
    if (l < 48)
      *(uint32_t*)(sA + (l >> 4) * 2112 + 2048 + (l & 15) * 4) = 0x3F803F80u;
    asm volatile("s_waitcnt lgkmcnt(0)" ::: "memory");

    const int tq0 = 2 * sup, tq1 = 2 * sup + 1;
    const int qidx0 = sup * 64 + lane31, qidx1 = qidx0 + 32;
    const bf16x8 qf0 = *(const bf16x8*)(Qp + (size_t)qidx0 * D + 8 * h);
    const bf16x8 qf1 = *(const bf16x8*)(Qp + (size_t)qidx1 * D + 8 * h);
    f32x16 acc0 = {}, acc1 = {};

    const int cnt = (w < ns) ? ((ns - w + 7) >> 3) : 0;
    auto stage = [&](char* slot, int i) {         // always exactly 2 loads
      int s = w + 8 * i;
      if (s > NTILE - 1) s = NTILE - 1;           // clamped: always legal
      gload_lds16((const char*)Kp + (size_t)s * 1024 + (size_t)l * 16, slot);
      gload_lds16((const char*)Vp + (size_t)s * 1088 + (size_t)l * 16,
                  slot + 1024);
    };
    stage(sA, 0); stage(sB, 1); stage(sC, 2);     // prologue: depth 3

    char* cur = sA; char* nx1 = sB; char* nx2 = sC;
#pragma unroll 1
    for (int i = 0; i < cnt; ++i) {
      const int s = w + 8 * i;
      asm volatile("s_waitcnt vmcnt(4)" ::: "memory");  // slot `cur` landed
      __builtin_amdgcn_sched_barrier(0);
      const unsigned short* kb = (const unsigned short*)cur;
      const unsigned short* vb = (const unsigned short*)(cur + 1024);
      const bf16x8 kf = *(const bf16x8*)(kb + lane31 * 16 + 8 * h);
      const bf16x8 vA = *(const bf16x8*)(vb + dvx * 32 + 16 * h);
      const bf16x8 vBv = *(const bf16x8*)(vb + dvx * 32 + 16 * h + 8);
      half_step(kf, vA, vBv, qf0, acc0, s, tq0, qidx0);
      half_step(kf, vA, vBv, qf1, acc1, s, tq1, qidx1);
      asm volatile("s_waitcnt lgkmcnt(0)" ::: "memory");  // reads retired
      __builtin_amdgcn_sched_barrier(0);
      stage(cur, i + 3);                 // reuse just-consumed slot
      char* t = cur; cur = nx1; nx1 = nx2; nx2 = t;
    }
    asm volatile("s_waitcnt vmcnt(0)" ::: "memory");  // tail stages land
    __syncthreads();                     // kv region quiesced for Po reuse

#pragma unroll
    for (int r = 0; r < 8; ++r) {
      const int dj = (r & 3) + 8 * (r >> 2) + 4 * h;
      Po[w][0][lane31][dj] = acc0[r];
      Po[w][1][lane31][dj] = acc1[r];
    }
    if (l < 32) {                        // row 16 = sum(P)  (ones row)
      Po[w][0][lane31][16] = acc0[8];
      Po[w][1][lane31][16] = acc1[8];
    }
  };

  auto merge = [&](int sup, int tt) {
    const int qidx = sup * 64 + tt * 32 + lane31;
    float L = 0.f, od[8] = {};
#pragma unroll
    for (int p = 0; p < 8; ++p) {
      L += Po[p][tt][lane31][16];
#pragma unroll
      for (int r = 0; r < 8; ++r) {
        const int dj = (r & 3) + 8 * (r >> 2) + 4 * h;
        od[r] += Po[p][tt][lane31][dj];
      }
    }
    const float inv = 1.f / L;
    float* base = att + ((size_t)bh * T + qidx) * D;
    *(float4*)(base + 4 * h) =
        make_float4(od[0] * inv, od[1] * inv, od[2] * inv, od[3] * inv);
    *(float4*)(base + 8 + 4 * h) =
        make_float4(od[4] * inv, od[5] * inv, od[6] * inv, od[7] * inv);
  };

  run_phase(superA, nsA);
  __syncthreads();
  if (w < 2) merge(superA, w);
  __syncthreads();                       // Po consumed; slots reusable
  run_phase(superB, nsB);
  __syncthreads();
  if (w < 2) merge(superB, w);
}

// ---------------------------------------------------------------------------
// Kernel 3: output projection + bias (fp32).  Half-K staging, 512 blocks.
// (unchanged)
// ---------------------------------------------------------------------------
__global__ __launch_bounds__(256) void out_proj(
    const float* __restrict__ att, const float* __restrict__ Wp,
    const float* __restrict__ bp, float* __restrict__ out) {
  __shared__ float As[64][36];
  __shared__ float Bs[64][68];
  const int tid = threadIdx.x;
  const int t0 = blockIdx.x * 32;
  const int c0 = blockIdx.y * 64;
  const int tx = tid & 15, ty = tid >> 4;

  float acc[2][4] = {};
#pragma unroll 1
  for (int kh = 0; kh < 2; ++kh) {
    if (kh) __syncthreads();
    for (int f = tid; f < 512; f += 256) {
      const int mm = f & 31;
      const int cpl = (f >> 5) << 2;
      const int cp = kh * 64 + cpl;
      const int tr = t0 + mm;
      const int b = tr >> 12, t = tr & (T - 1);
      const int hh = cp >> 4, d0 = cp & 15;
      const float4 v =
          *(const float4*)(att + (((size_t)b * H + hh) * T + t) * D + d0);
      As[cpl + 0][mm] = v.x; As[cpl + 1][mm] = v.y;
      As[cpl + 2][mm] = v.z; As[cpl + 3][mm] = v.w;
    }
    for (int f = tid; f < 1024; f += 256) {
      const int n = f >> 4;
      const int kk = (f & 15) << 2;
      const float4 v =
          *(const float4*)(Wp + (size_t)(c0 + n) * C + kh * 64 + kk);
      Bs[kk + 0][n] = v.x; Bs[kk + 1][n] = v.y;
      Bs[kk + 2][n] = v.z; Bs[kk + 3][n] = v.w;
    }
    __syncthreads();
#pragma unroll 8
    for (int k = 0; k < 64; ++k) {
      const float2 a = *(const float2*)&As[k][ty * 2];
      const float4 b = *(const float4*)&Bs[k][tx * 4];
      const float av[2] = {a.x, a.y};
      const float bv[4] = {b.x, b.y, b.z, b.w};
#pragma unroll
      for (int i = 0; i < 2; ++i)
#pragma unroll
        for (int jj = 0; jj < 4; ++jj)
          acc[i][jj] = fmaf(av[i], bv[jj], acc[i][jj]);
    }
  }

  const float4 bias = *(const float4*)(bp + c0 + tx * 4);
#pragma unroll
  for (int i = 0; i < 2; ++i) {
    const int tr = t0 + ty * 2 + i;
    const float4 v = make_float4(acc[i][0] + bias.x, acc[i][1] + bias.y,
                                 acc[i][2] + bias.z, acc[i][3] + bias.w);
    *(float4*)(out + (size_t)tr * C + c0 + tx * 4) = v;
  }
}

}  // namespace

extern "C" void kernel_launch(void* const* d_in, const int* in_sizes, int n_in,
                              void* d_out, int out_size, void* d_ws, size_t ws_size,
                              hipStream_t stream) {
  // setup_inputs order: x, Wk, Wq, Wv, Wp, bp
  const float* x  = (const float*)d_in[0];
  const float* Wk = (const float*)d_in[1];
  const float* Wq = (const float*)d_in[2];
  const float* Wv = (const float*)d_in[3];
  const float* Wp = (const float*)d_in[4];
  const float* bp = (const float*)d_in[5];

  float* att = (float*)d_ws;                             // 4 MiB fp32
  unsigned short* Qbf = (unsigned short*)(att + PLANE);  // 2 MiB bf16
  unsigned short* Kbf = Qbf + PLANE;                     // 2 MiB
  unsigned short* Vtb = Kbf + PLANE;                     // ~2.13 MiB (VROWS=17)

  qkv_proj<<<dim3(128, 6), 512, 0, stream>>>(x, Wq, Wk, Wv, Qbf, Kbf, Vtb);
  attn_fwd<<<dim3(512), 512, 0, stream>>>(Qbf, Kbf, Vtb, att);
  out_proj<<<dim3(256, 2), 256, 0, stream>>>(att, Wp, bp, (float*)d_out);
}

// Round 21
// 53.670 us; speedup vs baseline: 1.3407x; 1.1076x over previous
//
#include <hip/hip_runtime.h>

namespace {

constexpr int T = 4096;
constexpr int C = 128;
constexpr int H = 8;
constexpr int D = 16;
constexpr int BH = 16;                         // B*H
constexpr size_t PLANE = (size_t)BH * T * D;   // 1,048,576 elements per tensor
constexpr int NTILE = T / 32;                  // 128 key-tiles per bh
constexpr int VROWS = 17;                      // 16 d-rows + 1 ones-row
constexpr size_t VPLANE = (size_t)NTILE * VROWS * 32;  // per-bh Vt elements

using bf16x8 = __attribute__((ext_vector_type(8))) short;
using f32x16 = __attribute__((ext_vector_type(16))) float;

__device__ __forceinline__ uint32_t cvt_pk_bf16(float lo, float hi) {
  uint32_t r;
  asm("v_cvt_pk_bf16_f32 %0, %1, %2" : "=v"(r) : "v"(lo), "v"(hi));
  return r;
}
__device__ __forceinline__ float exp2_hw(float x) {
  float r;
  asm("v_exp_f32 %0, %1" : "=v"(r) : "v"(x));
  return r;
}
// async global->LDS, 16B per lane: lds dest = uniform base + lane*16.
typedef const __attribute__((address_space(1))) void* gas_t;
typedef __attribute__((address_space(3))) void* las_t;
__device__ __forceinline__ void gload_lds16(const void* g, void* l) {
  __builtin_amdgcn_global_load_lds((gas_t)g, (las_t)l, 16, 0, 0);
}

// ---------------------------------------------------------------------------
// Kernel 1: QKV projection -> bf16.  QUARTER-K staging: Xs/Ws are [32][68]
// (17.4KB total vs 34.8KB) -> 8 blocks/CU = 32 waves/CU (was 3 blocks/12
// waves; r19 diag measured 16.4us = 3x the 5us VALU floor, latency-bound).
// Four stage+compute passes, k globally ascending -> per-output fmaf chain
// identical to r12..r19 -> BIT-IDENTICAL results.  256 thr, 4x4 acc (the
// r20 512-thr/2x4 variant regressed).  No launch_bounds min-wave cap.
//   Qbf[bh][t][d] (pre-scaled by D^-1/2*log2e), Kbf[bh][t][d],
//   Vt TILED+ONES+SWIZZLED: [bh][t/32][17][32], V written as 1KB bursts.
// ---------------------------------------------------------------------------
__global__ __launch_bounds__(256) void qkv_proj(
    const float* __restrict__ x, const float* __restrict__ Wq,
    const float* __restrict__ Wk, const float* __restrict__ Wv,
    unsigned short* __restrict__ Qbf, unsigned short* __restrict__ Kbf,
    unsigned short* __restrict__ Vt) {
  __shared__ __align__(16) char smem[17408];   // Xs[32][68] | Ws[32][68]
  float (*Xs)[68] = reinterpret_cast<float(*)[68]>(smem);
  float (*Ws)[68] = reinterpret_cast<float(*)[68]>(smem + 8704);
  const int tid = threadIdx.x;
  const int bm = blockIdx.x;            // 128 row blocks
  const int bn = blockIdx.y;            // 6 col blocks
  const int mat = bn >> 1;              // 0=Q 1=K 2=V
  const int c0 = (bn & 1) * 64;
  const float* W = (mat == 0) ? Wq : (mat == 1) ? Wk : Wv;
  const int t0 = bm * 64;
  const int tx = tid & 15, ty = tid >> 4;

  float acc[4][4] = {};
#pragma unroll 1
  for (int kh = 0; kh < 4; ++kh) {
    if (kh) __syncthreads();            // prior pass's reads complete
    for (int f = tid; f < 512; f += 256) {
      const int m = f >> 3;             // 0..63
      const int k4 = (f & 7) << 2;      // 0..28
      const float4 v =
          *(const float4*)(x + (size_t)(t0 + m) * C + kh * 32 + k4);
      Xs[k4 + 0][m] = v.x; Xs[k4 + 1][m] = v.y;
      Xs[k4 + 2][m] = v.z; Xs[k4 + 3][m] = v.w;
      const float4 u =
          *(const float4*)(W + (size_t)(c0 + m) * C + kh * 32 + k4);
      Ws[k4 + 0][m] = u.x; Ws[k4 + 1][m] = u.y;
      Ws[k4 + 2][m] = u.z; Ws[k4 + 3][m] = u.w;
    }
    __syncthreads();
#pragma unroll 8
    for (int k = 0; k < 32; ++k) {
      const float4 a = *(const float4*)&Xs[k][ty * 4];
      const float4 b = *(const float4*)&Ws[k][tx * 4];
      const float av[4] = {a.x, a.y, a.z, a.w};
      const float bv[4] = {b.x, b.y, b.z, b.w};
#pragma unroll
      for (int i = 0; i < 4; ++i)
#pragma unroll
        for (int j = 0; j < 4; ++j) acc[i][j] = fmaf(av[i], bv[j], acc[i][j]);
    }
  }
  __syncthreads();  // done reading Xs/Ws -> reuse as bf16 staging

  unsigned short* Ls = (unsigned short*)smem;   // [64][72] bf16, 9216B
  if (mat < 2) {
    const float sc = (mat == 0) ? 0.25f * 1.4426950408889634f : 1.0f;
#pragma unroll
    for (int i = 0; i < 4; ++i) {                 // Ls[t][c] packed bf16
      const uint32_t u0 = cvt_pk_bf16(acc[i][0] * sc, acc[i][1] * sc);
      const uint32_t u1 = cvt_pk_bf16(acc[i][2] * sc, acc[i][3] * sc);
      *(uint32_t*)&Ls[(ty * 4 + i) * 72 + tx * 4]     = u0;
      *(uint32_t*)&Ls[(ty * 4 + i) * 72 + tx * 4 + 2] = u1;
    }
    __syncthreads();
    unsigned short* dst = (mat == 0) ? Qbf : Kbf;
    const int lane = tid & 63, hp = tid >> 6;     // wave hp -> head-slot hp
    const int tr = t0 + lane, b = tr >> 12, t = tr & (T - 1);
    const int head = (c0 >> 4) + hp;
    unsigned short* base = dst + (((size_t)(b * H + head)) * T + t) * D;
#pragma unroll
    for (int p = 0; p < 2; ++p)                   // 2x16B per lane, coalesced
      *(uint4*)(base + p * 8) = *(const uint4*)&Ls[lane * 72 + hp * 16 + p * 8];
  } else {
#pragma unroll
    for (int j = 0; j < 4; ++j) {                 // Ls[c][t] (transposed)
      const uint32_t u0 = cvt_pk_bf16(acc[0][j], acc[1][j]);
      const uint32_t u1 = cvt_pk_bf16(acc[2][j], acc[3][j]);
      *(uint32_t*)&Ls[(tx * 4 + j) * 72 + ty * 4]     = u0;
      *(uint32_t*)&Ls[(tx * 4 + j) * 72 + ty * 4 + 2] = u1;
    }
    __syncthreads();
    // coalesced V writer (r19): wave w2 handles units 2*w2, 2*w2+1
    // (unit = head-offset ho x tile ti).  Lane l packs the 8 swizzled bf16
    // of row d=l>>2, group g=l&3 and stores 16B at tilebase + l*16:
    // one contiguous 1024B burst per unit.
    const int w2 = tid >> 6, l = tid & 63;
    const int b = t0 >> 12;
    const int tile0 = (t0 & (T - 1)) >> 5;        // t0 is 64-aligned
    const int d = l >> 2, g = l & 3;
    const int kbase = 16 * (g & 1) + 4 * (g >> 1);
#pragma unroll
    for (int u = 2 * w2; u < 2 * w2 + 2; ++u) {
      const int ho = u >> 1, ti = u & 1;
      const int head = (c0 >> 4) + ho;
      const unsigned short* Lsrc = Ls + (ho * 16 + d) * 72 + ti * 32;
      uint32_t pk[4];
#pragma unroll
      for (int p = 0; p < 4; ++p) {
        const int kk = kbase + 8 * (p >> 1) + 2 * (p & 1);
        pk[p] = (uint32_t)Lsrc[kk] | ((uint32_t)Lsrc[kk + 1] << 16);
      }
      unsigned short* tb =
          Vt + ((size_t)(b * H + head) * NTILE + tile0 + ti) * (VROWS * 32);
      *(uint4*)((char*)tb + l * 16) = make_uint4(pk[0], pk[1], pk[2], pk[3]);
    }
    // ones row (row 16) for the 4 heads x 2 tiles this block owns
    if (tid < 8) {
      const int headx = (c0 >> 4) + (tid >> 1);
      const int tilex = tile0 + (tid & 1);
      unsigned short* orow =
          Vt + (((size_t)(b * H + headx) * NTILE + tilex) * VROWS + 16) * 32;
      const uint4 ones = make_uint4(0x3F803F80u, 0x3F803F80u,
                                    0x3F803F80u, 0x3F803F80u);
#pragma unroll
      for (int q = 0; q < 4; ++q) *(uint4*)(orow + q * 8) = ones;
    }
  }
}

// ---------------------------------------------------------------------------
// Kernel 2: causal flash attention (r18: barrier-free per-wave LDS pipeline,
// counted vmcnt, no-max softmax, ones-row denominator).  Unchanged.
// ---------------------------------------------------------------------------
__global__ __launch_bounds__(512, 2) void attn_fwd(
    const unsigned short* __restrict__ Qbf, const unsigned short* __restrict__ Kbf,
    const unsigned short* __restrict__ Vt, float* __restrict__ att) {
  __shared__ __align__(16) char smem[50688];   // slots [8][3][2112] U Po
  float (*Po)[2][32][17] = reinterpret_cast<float(*)[2][32][17]>(smem);
  const int tid = threadIdx.x;
  const int w = tid >> 6, l = tid & 63;
  const int lane31 = l & 31, h = l >> 5;
  const int dvx = (lane31 == 16) ? 16 : (l & 15);  // lane31==16 -> ones row
  const int ib = blockIdx.x;
  const int bh = 2 * (ib & 7) + ((ib >> 3) & 1);   // XCD x <- bh {2x, 2x+1}
  const int j = ib >> 4;                           // 0..31
  const int superA = 63 - j, superB = j;
  const int nsA = 2 * superA + 2, nsB = 2 * superB + 2;  // nsA >= 66

  const unsigned short* Qp = Qbf + (size_t)bh * T * D;
  const unsigned short* Kp = Kbf + (size_t)bh * T * D;
  const unsigned short* Vp = Vt + (size_t)bh * VPLANE;

  auto half_step = [&](const bf16x8& kf, const bf16x8& vA, const bf16x8& vB,
                       const bf16x8& qf, f32x16& acc, int s, int tq,
                       int qidx) {
    f32x16 sc = {};
    __builtin_amdgcn_s_setprio(1);
    sc = __builtin_amdgcn_mfma_f32_32x32x16_bf16(kf, qf, sc, 0, 0, 0);
    __builtin_amdgcn_s_setprio(0);
    if (s >= tq) {                      // diag or dead step: causal mask
      const int k0 = s * 32;
#pragma unroll
      for (int r = 0; r < 16; ++r) {
        const int key = k0 + (r & 3) + 8 * (r >> 2) + 4 * h;
        if (key > qidx) sc[r] = -1e30f;
      }
    }
#pragma unroll
    for (int r = 0; r < 16; ++r) sc[r] = exp2_hw(sc[r]);  // no-max softmax
    union PF { bf16x8 v; uint32_t u[4]; } pa, pb;
    pa.u[0] = cvt_pk_bf16(sc[0], sc[1]);
    pa.u[1] = cvt_pk_bf16(sc[2], sc[3]);
    pa.u[2] = cvt_pk_bf16(sc[4], sc[5]);
    pa.u[3] = cvt_pk_bf16(sc[6], sc[7]);
    pb.u[0] = cvt_pk_bf16(sc[8], sc[9]);
    pb.u[1] = cvt_pk_bf16(sc[10], sc[11]);
    pb.u[2] = cvt_pk_bf16(sc[12], sc[13]);
    pb.u[3] = cvt_pk_bf16(sc[14], sc[15]);
    __builtin_amdgcn_s_setprio(1);
    acc = __builtin_amdgcn_mfma_f32_32x32x16_bf16(vA, pa.v, acc, 0, 0, 0);
    acc = __builtin_amdgcn_mfma_f32_32x32x16_bf16(vB, pb.v, acc, 0, 0, 0);
    __builtin_amdgcn_s_setprio(0);
  };

  auto run_phase = [&](int sup, int ns) {
    char* sA = smem + w * 6336;         // my 3 slots
    char* sB = sA + 2112;
    char* sC = sA + 4224;
    // prefill constant bf16(1.0) ones rows of my 3 slots (wave-private)
    if (l < 48)
      *(uint32_t*)(sA + (l >> 4) * 2112 + 2048 + (l & 15) * 4) = 0x3F803F80u;
    asm volatile("s_waitcnt lgkmcnt(0)" ::: "memory");

    const int tq0 = 2 * sup, tq1 = 2 * sup + 1;
    const int qidx0 = sup * 64 + lane31, qidx1 = qidx0 + 32;
    const bf16x8 qf0 = *(const bf16x8*)(Qp + (size_t)qidx0 * D + 8 * h);
    const bf16x8 qf1 = *(const bf16x8*)(Qp + (size_t)qidx1 * D + 8 * h);
    f32x16 acc0 = {}, acc1 = {};

    const int cnt = (w < ns) ? ((ns - w + 7) >> 3) : 0;
    auto stage = [&](char* slot, int i) {         // always exactly 2 loads
      int s = w + 8 * i;
      if (s > NTILE - 1) s = NTILE - 1;           // clamped: always legal
      gload_lds16((const char*)Kp + (size_t)s * 1024 + (size_t)l * 16, slot);
      gload_lds16((const char*)Vp + (size_t)s * 1088 + (size_t)l * 16,
                  slot + 1024);
    };
    stage(sA, 0); stage(sB, 1); stage(sC, 2);     // prologue: depth 3

    char* cur = sA; char* nx1 = sB; char* nx2 = sC;
#pragma unroll 1
    for (int i = 0; i < cnt; ++i) {
      const int s = w + 8 * i;
      asm volatile("s_waitcnt vmcnt(4)" ::: "memory");  // slot `cur` landed
      __builtin_amdgcn_sched_barrier(0);
      const unsigned short* kb = (const unsigned short*)cur;
      const unsigned short* vb = (const unsigned short*)(cur + 1024);
      const bf16x8 kf = *(const bf16x8*)(kb + lane31 * 16 + 8 * h);
      const bf16x8 vA = *(const bf16x8*)(vb + dvx * 32 + 16 * h);
      const bf16x8 vBv = *(const bf16x8*)(vb + dvx * 32 + 16 * h + 8);
      half_step(kf, vA, vBv, qf0, acc0, s, tq0, qidx0);
      half_step(kf, vA, vBv, qf1, acc1, s, tq1, qidx1);
      asm volatile("s_waitcnt lgkmcnt(0)" ::: "memory");  // reads retired
      __builtin_amdgcn_sched_barrier(0);
      stage(cur, i + 3);                 // reuse just-consumed slot
      char* t = cur; cur = nx1; nx1 = nx2; nx2 = t;
    }
    asm volatile("s_waitcnt vmcnt(0)" ::: "memory");  // tail stages land
    __syncthreads();                     // kv region quiesced for Po reuse

#pragma unroll
    for (int r = 0; r < 8; ++r) {
      const int dj = (r & 3) + 8 * (r >> 2) + 4 * h;
      Po[w][0][lane31][dj] = acc0[r];
      Po[w][1][lane31][dj] = acc1[r];
    }
    if (l < 32) {                        // row 16 = sum(P)  (ones row)
      Po[w][0][lane31][16] = acc0[8];
      Po[w][1][lane31][16] = acc1[8];
    }
  };

  auto merge = [&](int sup, int tt) {
    const int qidx = sup * 64 + tt * 32 + lane31;
    float L = 0.f, od[8] = {};
#pragma unroll
    for (int p = 0; p < 8; ++p) {
      L += Po[p][tt][lane31][16];
#pragma unroll
      for (int r = 0; r < 8; ++r) {
        const int dj = (r & 3) + 8 * (r >> 2) + 4 * h;
        od[r] += Po[p][tt][lane31][dj];
      }
    }
    const float inv = 1.f / L;
    float* base = att + ((size_t)bh * T + qidx) * D;
    *(float4*)(base + 4 * h) =
        make_float4(od[0] * inv, od[1] * inv, od[2] * inv, od[3] * inv);
    *(float4*)(base + 8 + 4 * h) =
        make_float4(od[4] * inv, od[5] * inv, od[6] * inv, od[7] * inv);
  };

  run_phase(superA, nsA);
  __syncthreads();
  if (w < 2) merge(superA, w);
  __syncthreads();                       // Po consumed; slots reusable
  run_phase(superB, nsB);
  __syncthreads();
  if (w < 2) merge(superB, w);
}

// ---------------------------------------------------------------------------
// Kernel 3: output projection + bias (fp32).  Half-K staging, 512 blocks.
// (unchanged from r18)
// ---------------------------------------------------------------------------
__global__ __launch_bounds__(256) void out_proj(
    const float* __restrict__ att, const float* __restrict__ Wp,
    const float* __restrict__ bp, float* __restrict__ out) {
  __shared__ float As[64][36];
  __shared__ float Bs[64][68];
  const int tid = threadIdx.x;
  const int t0 = blockIdx.x * 32;
  const int c0 = blockIdx.y * 64;
  const int tx = tid & 15, ty = tid >> 4;

  float acc[2][4] = {};
#pragma unroll 1
  for (int kh = 0; kh < 2; ++kh) {
    if (kh) __syncthreads();
    for (int f = tid; f < 512; f += 256) {
      const int mm = f & 31;
      const int cpl = (f >> 5) << 2;
      const int cp = kh * 64 + cpl;
      const int tr = t0 + mm;
      const int b = tr >> 12, t = tr & (T - 1);
      const int hh = cp >> 4, d0 = cp & 15;
      const float4 v =
          *(const float4*)(att + (((size_t)b * H + hh) * T + t) * D + d0);
      As[cpl + 0][mm] = v.x; As[cpl + 1][mm] = v.y;
      As[cpl + 2][mm] = v.z; As[cpl + 3][mm] = v.w;
    }
    for (int f = tid; f < 1024; f += 256) {
      const int n = f >> 4;
      const int kk = (f & 15) << 2;
      const float4 v =
          *(const float4*)(Wp + (size_t)(c0 + n) * C + kh * 64 + kk);
      Bs[kk + 0][n] = v.x; Bs[kk + 1][n] = v.y;
      Bs[kk + 2][n] = v.z; Bs[kk + 3][n] = v.w;
    }
    __syncthreads();
#pragma unroll 8
    for (int k = 0; k < 64; ++k) {
      const float2 a = *(const float2*)&As[k][ty * 2];
      const float4 b = *(const float4*)&Bs[k][tx * 4];
      const float av[2] = {a.x, a.y};
      const float bv[4] = {b.x, b.y, b.z, b.w};
#pragma unroll
      for (int i = 0; i < 2; ++i)
#pragma unroll
        for (int jj = 0; jj < 4; ++jj)
          acc[i][jj] = fmaf(av[i], bv[jj], acc[i][jj]);
    }
  }

  const float4 bias = *(const float4*)(bp + c0 + tx * 4);
#pragma unroll
  for (int i = 0; i < 2; ++i) {
    const int tr = t0 + ty * 2 + i;
    const float4 v = make_float4(acc[i][0] + bias.x, acc[i][1] + bias.y,
                                 acc[i][2] + bias.z, acc[i][3] + bias.w);
    *(float4*)(out + (size_t)tr * C + c0 + tx * 4) = v;
  }
}

}  // namespace

extern "C" void kernel_launch(void* const* d_in, const int* in_sizes, int n_in,
                              void* d_out, int out_size, void* d_ws, size_t ws_size,
                              hipStream_t stream) {
  // setup_inputs order: x, Wk, Wq, Wv, Wp, bp
  const float* x  = (const float*)d_in[0];
  const float* Wk = (const float*)d_in[1];
  const float* Wq = (const float*)d_in[2];
  const float* Wv = (const float*)d_in[3];
  const float* Wp = (const float*)d_in[4];
  const float* bp = (const float*)d_in[5];

  float* att = (float*)d_ws;                             // 4 MiB fp32
  unsigned short* Qbf = (unsigned short*)(att + PLANE);  // 2 MiB bf16
  unsigned short* Kbf = Qbf + PLANE;                     // 2 MiB
  unsigned short* Vtb = Kbf + PLANE;                     // ~2.13 MiB (VROWS=17)

  qkv_proj<<<dim3(128, 6), 256, 0, stream>>>(x, Wq, Wk, Wv, Qbf, Kbf, Vtb);
  attn_fwd<<<dim3(512), 512, 0, stream>>>(Qbf, Kbf, Vtb, att);
  out_proj<<<dim3(256, 2), 256, 0, stream>>>(att, Wp, bp, (float*)d_out);
}